// Round 1
// baseline (441.716 us; speedup 1.0000x reference)
//
#include <hip/hip_runtime.h>

#define BATCH 16
#define N_DIM 4096
#define C_DIM 512
#define BK 64
#define LDK 72  // padded LDS row stride in bf16 (144 B = 36 dwords -> 2-way max on b128, free)

typedef short bf16x8 __attribute__((ext_vector_type(8)));
typedef float f32x4 __attribute__((ext_vector_type(4)));

static __device__ __forceinline__ short f2bf(float f) {
    union { float f; unsigned u; } v; v.f = f;
    unsigned r = v.u + 0x7FFFu + ((v.u >> 16) & 1u);  // RNE
    return (short)(r >> 16);
}

// ---------------------------------------------------------------------------
// Kernel 1: S[b,c,d] = sum_n X[b,n,c] * X[b,n,d]   (Gram, bf16 MFMA)
// block = 256 (4 waves), tile 64x64, BK=64. LDS holds transposed tiles [c][k].
// ---------------------------------------------------------------------------
__global__ __launch_bounds__(256) void gram_kernel(const float* __restrict__ x,
                                                   float* __restrict__ S) {
    const int b  = blockIdx.z;
    const int c0 = blockIdx.x * 64;
    const int d0 = blockIdx.y * 64;
    const float* __restrict__ X = x + (size_t)b * N_DIM * C_DIM;

    __shared__ short As[64 * LDK];  // [c_local][k_local]
    __shared__ short Bs[64 * LDK];  // [d_local][k_local]

    const int t    = threadIdx.x;
    const int lane = t & 63;
    const int wave = t >> 6;
    const int wm   = (wave >> 1) * 32;
    const int wn   = (wave & 1) * 32;
    const int fm   = lane & 15;   // frag row/col within 16
    const int quad = lane >> 4;   // 0..3

    // staging: this thread loads column (c0+cs)/(d0+cs), k rows kb..kb+15
    const int cs = t & 63;
    const int kb = (t >> 6) * 16;

    f32x4 acc[2][2];
#pragma unroll
    for (int i = 0; i < 2; ++i)
#pragma unroll
        for (int j = 0; j < 2; ++j) acc[i][j] = (f32x4){0.f, 0.f, 0.f, 0.f};

    for (int k0 = 0; k0 < N_DIM; k0 += BK) {
        short ha[16], hb[16];
        const float* pa = X + (size_t)(k0 + kb) * C_DIM + c0 + cs;
        const float* pb = X + (size_t)(k0 + kb) * C_DIM + d0 + cs;
#pragma unroll
        for (int i = 0; i < 16; ++i) {
            ha[i] = f2bf(pa[(size_t)i * C_DIM]);
            hb[i] = f2bf(pb[(size_t)i * C_DIM]);
        }
        __syncthreads();  // previous iteration's LDS reads done
#pragma unroll
        for (int h = 0; h < 2; ++h) {
            bf16x8 va, vb;
#pragma unroll
            for (int j = 0; j < 8; ++j) { va[j] = ha[h * 8 + j]; vb[j] = hb[h * 8 + j]; }
            *(bf16x8*)&As[cs * LDK + kb + h * 8] = va;
            *(bf16x8*)&Bs[cs * LDK + kb + h * 8] = vb;
        }
        __syncthreads();
#pragma unroll
        for (int ks = 0; ks < BK; ks += 32) {
            bf16x8 af[2], bfr[2];
#pragma unroll
            for (int s = 0; s < 2; ++s) {
                af[s]  = *(const bf16x8*)&As[(wm + s * 16 + fm) * LDK + ks + quad * 8];
                bfr[s] = *(const bf16x8*)&Bs[(wn + s * 16 + fm) * LDK + ks + quad * 8];
            }
#pragma unroll
            for (int i = 0; i < 2; ++i)
#pragma unroll
                for (int j = 0; j < 2; ++j)
                    acc[i][j] = __builtin_amdgcn_mfma_f32_16x16x32_bf16(af[i], bfr[j], acc[i][j], 0, 0, 0);
        }
    }

    // C/D layout (m89-verified): col = lane&15, row = quad*4 + reg
    float* __restrict__ Sb = S + (size_t)b * C_DIM * C_DIM;
#pragma unroll
    for (int i = 0; i < 2; ++i)
#pragma unroll
        for (int j = 0; j < 2; ++j)
#pragma unroll
            for (int r = 0; r < 4; ++r) {
                int cc = c0 + wm + i * 16 + quad * 4 + r;
                int dd = d0 + wn + j * 16 + fm;
                Sb[(size_t)cc * C_DIM + dd] = acc[i][j][r];
            }
}

// ---------------------------------------------------------------------------
// Kernel 2: attn[b,c,:] = softmax(S[b,c,:]) -> bf16, coalesced [c][d] layout
// one wave per row (512 elems = 8/lane)
// ---------------------------------------------------------------------------
__global__ __launch_bounds__(256) void softmax_kernel(const float* __restrict__ S,
                                                      short* __restrict__ attn) {
    const int row  = blockIdx.x * 4 + (threadIdx.x >> 6);
    const int lane = threadIdx.x & 63;
    const float* __restrict__ r = S + (size_t)row * C_DIM + lane * 8;

    float v[8];
    *(f32x4*)&v[0] = *(const f32x4*)&r[0];
    *(f32x4*)&v[4] = *(const f32x4*)&r[4];

    float mx = v[0];
#pragma unroll
    for (int j = 1; j < 8; ++j) mx = fmaxf(mx, v[j]);
#pragma unroll
    for (int off = 32; off > 0; off >>= 1) mx = fmaxf(mx, __shfl_xor(mx, off));

    float sum = 0.f;
#pragma unroll
    for (int j = 0; j < 8; ++j) { v[j] = __expf(v[j] - mx); sum += v[j]; }
#pragma unroll
    for (int off = 32; off > 0; off >>= 1) sum += __shfl_xor(sum, off);

    const float inv = 1.0f / sum;
    bf16x8 hv;
#pragma unroll
    for (int j = 0; j < 8; ++j) hv[j] = f2bf(v[j] * inv);
    *(bf16x8*)&attn[(size_t)row * C_DIM + lane * 8] = hv;
}

// ---------------------------------------------------------------------------
// Kernel 3: V = X_bf16 @ attn ; out = beta*V + x
// A (X) is K-contiguous in global (no transpose); B (attn) transposed in LDS.
// ---------------------------------------------------------------------------
__global__ __launch_bounds__(256) void av_kernel(const float* __restrict__ x,
                                                 const short* __restrict__ attn,
                                                 const float* __restrict__ beta,
                                                 float* __restrict__ out) {
    const int b  = blockIdx.z;
    const int n0 = blockIdx.x * 64;
    const int d0 = blockIdx.y * 64;
    const float* __restrict__ X = x + (size_t)b * N_DIM * C_DIM;
    const short* __restrict__ A = attn + (size_t)b * C_DIM * C_DIM;

    __shared__ short As[64 * LDK];  // [n_local][c_local]
    __shared__ short Bs[64 * LDK];  // [d_local][c_local]

    const int t    = threadIdx.x;
    const int lane = t & 63;
    const int wave = t >> 6;
    const int wm   = (wave >> 1) * 32;
    const int wn   = (wave & 1) * 32;
    const int fm   = lane & 15;
    const int quad = lane >> 4;

    const int ds = t & 63;          // B staging: d column
    const int cb = (t >> 6) * 16;   // B staging: c rows cb..cb+15

    f32x4 acc[2][2];
#pragma unroll
    for (int i = 0; i < 2; ++i)
#pragma unroll
        for (int j = 0; j < 2; ++j) acc[i][j] = (f32x4){0.f, 0.f, 0.f, 0.f};

    for (int k0 = 0; k0 < C_DIM; k0 += BK) {
        // --- A tile: 64n x 64c fp32, straight (c contiguous) ---
        float fa[2][8];
#pragma unroll
        for (int rep = 0; rep < 2; ++rep) {
            int g = t + 256 * rep;
            int n_l = g >> 3, c8 = (g & 7) * 8;
            const float* p = X + (size_t)(n0 + n_l) * C_DIM + k0 + c8;
            *(f32x4*)&fa[rep][0] = *(const f32x4*)&p[0];
            *(f32x4*)&fa[rep][4] = *(const f32x4*)&p[4];
        }
        // --- B tile: attn[c][d] -> Bs[d][c] (transpose) ---
        short hb[16];
        const short* pb = A + (size_t)(k0 + cb) * C_DIM + d0 + ds;
#pragma unroll
        for (int i = 0; i < 16; ++i) hb[i] = pb[(size_t)i * C_DIM];

        __syncthreads();
#pragma unroll
        for (int rep = 0; rep < 2; ++rep) {
            int g = t + 256 * rep;
            int n_l = g >> 3, c8 = (g & 7) * 8;
            bf16x8 va;
#pragma unroll
            for (int j = 0; j < 8; ++j) va[j] = f2bf(fa[rep][j]);
            *(bf16x8*)&As[n_l * LDK + c8] = va;
        }
#pragma unroll
        for (int h = 0; h < 2; ++h) {
            bf16x8 vb;
#pragma unroll
            for (int j = 0; j < 8; ++j) vb[j] = hb[h * 8 + j];
            *(bf16x8*)&Bs[ds * LDK + cb + h * 8] = vb;
        }
        __syncthreads();
#pragma unroll
        for (int ks = 0; ks < BK; ks += 32) {
            bf16x8 af[2], bfr[2];
#pragma unroll
            for (int s = 0; s < 2; ++s) {
                af[s]  = *(const bf16x8*)&As[(wm + s * 16 + fm) * LDK + ks + quad * 8];
                bfr[s] = *(const bf16x8*)&Bs[(wn + s * 16 + fm) * LDK + ks + quad * 8];
            }
#pragma unroll
            for (int i = 0; i < 2; ++i)
#pragma unroll
                for (int j = 0; j < 2; ++j)
                    acc[i][j] = __builtin_amdgcn_mfma_f32_16x16x32_bf16(af[i], bfr[j], acc[i][j], 0, 0, 0);
        }
    }

    const float bv = beta[0];
#pragma unroll
    for (int i = 0; i < 2; ++i)
#pragma unroll
        for (int j = 0; j < 2; ++j)
#pragma unroll
            for (int r = 0; r < 4; ++r) {
                int nn = n0 + wm + i * 16 + quad * 4 + r;
                int dd = d0 + wn + j * 16 + fm;
                size_t idx = ((size_t)b * N_DIM + nn) * C_DIM + dd;
                out[idx] = bv * acc[i][j][r] + x[idx];
            }
}

extern "C" void kernel_launch(void* const* d_in, const int* in_sizes, int n_in,
                              void* d_out, int out_size, void* d_ws, size_t ws_size,
                              hipStream_t stream) {
    const float* x    = (const float*)d_in[0];
    const float* beta = (const float*)d_in[1];
    float* out = (float*)d_out;

    // workspace: S fp32 [16][512][512] then attn bf16 [16][512][512]
    float* S    = (float*)d_ws;
    short* attn = (short*)((char*)d_ws + (size_t)BATCH * C_DIM * C_DIM * sizeof(float));

    gram_kernel<<<dim3(C_DIM / 64, C_DIM / 64, BATCH), 256, 0, stream>>>(x, S);
    softmax_kernel<<<(BATCH * C_DIM) / 4, 256, 0, stream>>>(S, attn);
    av_kernel<<<dim3(N_DIM / 64, C_DIM / 64, BATCH), 256, 0, stream>>>(x, attn, beta, out);
}

// Round 2
// 412.196 us; speedup vs baseline: 1.0716x; 1.0716x over previous
//
#include <hip/hip_runtime.h>

#define BATCH 16
#define N_DIM 4096
#define C_DIM 512

typedef short bf16x8 __attribute__((ext_vector_type(8)));
typedef short bf16x4 __attribute__((ext_vector_type(4)));
typedef float f32x4 __attribute__((ext_vector_type(4)));
typedef int   i32x4 __attribute__((ext_vector_type(4)));

static __device__ __forceinline__ short f2bf(float f) {
    union { float f; unsigned u; } v; v.f = f;
    unsigned r = v.u + 0x7FFFu + ((v.u >> 16) & 1u);  // RNE
    return (short)(r >> 16);
}

#define GLOAD_LDS16(gp, lp) \
    __builtin_amdgcn_global_load_lds((const __attribute__((address_space(1))) void*)(gp), \
                                     (__attribute__((address_space(3))) void*)(lp), 16, 0, 0)

// ---------------------------------------------------------------------------
// K0: XhT[b][c][n] = bf16(x[b][n][c])  — cast + transpose via LDS
// grid (N/64, C/64, B), 256 threads. 64x64 tile.
// ---------------------------------------------------------------------------
__global__ __launch_bounds__(256) void transpose_cast_kernel(const float* __restrict__ x,
                                                             short* __restrict__ XhT) {
    const int b  = blockIdx.z;
    const int n0 = blockIdx.x * 64;
    const int c0 = blockIdx.y * 64;

    __shared__ short Ts[64 * 66];  // [c_local][n_local], pad 66 (row = 132 B, 33 dw)

    const int t  = threadIdx.x;
    const int nl = t >> 2;          // 0..63
    const int cb = (t & 3) * 16;    // 0,16,32,48

    const float* __restrict__ src = x + ((size_t)b * N_DIM + n0 + nl) * C_DIM + c0 + cb;
    short h[16];
#pragma unroll
    for (int s = 0; s < 4; ++s) {
        f32x4 v = *(const f32x4*)&src[s * 4];
#pragma unroll
        for (int q = 0; q < 4; ++q) h[s * 4 + q] = f2bf(v[q]);
    }
#pragma unroll
    for (int j = 0; j < 16; ++j) Ts[(cb + j) * 66 + nl] = h[j];
    __syncthreads();

    const int cl = t >> 2;          // 0..63
    const int ng = (t & 3) * 16;    // 0,16,32,48
    int buf[8];
#pragma unroll
    for (int q = 0; q < 8; ++q) buf[q] = *(const int*)&Ts[cl * 66 + ng + q * 2];

    short* __restrict__ dst = XhT + ((size_t)b * C_DIM + c0 + cl) * N_DIM + n0 + ng;
    i32x4 w0 = {buf[0], buf[1], buf[2], buf[3]};
    i32x4 w1 = {buf[4], buf[5], buf[6], buf[7]};
    *(i32x4*)&dst[0] = w0;
    *(i32x4*)&dst[8] = w1;
}

// ---------------------------------------------------------------------------
// K1: S[b,c,d] = sum_n XhT[b,c,n]*XhT[b,d,n]  — m97-style 128x128, BK=64
// grid (4, 4, 16), 256 threads (4 waves, 2x2, each 64x64 via 4x4 frags)
// ---------------------------------------------------------------------------
__global__ __launch_bounds__(256) void gram_kernel(const short* __restrict__ XhT,
                                                   float* __restrict__ S) {
    const int b  = blockIdx.z;
    const int c0 = blockIdx.x * 128;
    const int d0 = blockIdx.y * 128;
    const short* __restrict__ Xb = XhT + (size_t)b * C_DIM * N_DIM;

    __shared__ short As[128 * 64];  // [c_local][k], unpadded (global_load_lds layout)
    __shared__ short Bs[128 * 64];

    const int t    = threadIdx.x;
    const int lane = t & 63;
    const int wave = t >> 6;
    const int wm   = (wave >> 1) * 64;
    const int wn   = (wave & 1) * 64;
    const int fm   = lane & 15;
    const int quad = lane >> 4;

    const int rowA = t >> 3;        // 0..31
    const int koff = (t & 7) * 8;   // 0..56

    f32x4 acc[4][4];
#pragma unroll
    for (int i = 0; i < 4; ++i)
#pragma unroll
        for (int j = 0; j < 4; ++j) acc[i][j] = (f32x4){0.f, 0.f, 0.f, 0.f};

    for (int k0 = 0; k0 < N_DIM; k0 += 64) {
        __syncthreads();
#pragma unroll
        for (int rep = 0; rep < 4; ++rep) {
            const int r = rowA + rep * 32;
            GLOAD_LDS16(Xb + (size_t)(c0 + r) * N_DIM + k0 + koff, &As[r * 64 + koff]);
            GLOAD_LDS16(Xb + (size_t)(d0 + r) * N_DIM + k0 + koff, &Bs[r * 64 + koff]);
        }
        __syncthreads();
#pragma unroll
        for (int ks = 0; ks < 64; ks += 32) {
            bf16x8 af[4], bfr[4];
#pragma unroll
            for (int s = 0; s < 4; ++s) {
                af[s]  = *(const bf16x8*)&As[(wm + s * 16 + fm) * 64 + ks + quad * 8];
                bfr[s] = *(const bf16x8*)&Bs[(wn + s * 16 + fm) * 64 + ks + quad * 8];
            }
#pragma unroll
            for (int i = 0; i < 4; ++i)
#pragma unroll
                for (int j = 0; j < 4; ++j)
                    acc[i][j] = __builtin_amdgcn_mfma_f32_16x16x32_bf16(af[i], bfr[j], acc[i][j], 0, 0, 0);
        }
    }

    float* __restrict__ Sb = S + (size_t)b * C_DIM * C_DIM;
#pragma unroll
    for (int i = 0; i < 4; ++i)
#pragma unroll
        for (int j = 0; j < 4; ++j)
#pragma unroll
            for (int r = 0; r < 4; ++r) {
                const int cc = c0 + wm + i * 16 + quad * 4 + r;
                const int dd = d0 + wn + j * 16 + fm;
                Sb[(size_t)cc * C_DIM + dd] = acc[i][j][r];
            }
}

// ---------------------------------------------------------------------------
// K2: attnT[b][d][c] = softmax(S[b,:,:], axis=d)^T  (bf16), via LDS transpose
// grid (C/64, B), 256 threads. Block: 64 softmax rows -> transposed 64-col slab.
// ---------------------------------------------------------------------------
__global__ __launch_bounds__(256) void softmax_t_kernel(const float* __restrict__ S,
                                                        short* __restrict__ attnT) {
    const int c0 = blockIdx.x * 64;
    const int b  = blockIdx.y;

    __shared__ short T[512 * 66];  // [d][c_local], row = 132 B (33 dw)

    const int t    = threadIdx.x;
    const int lane = t & 63;
    const int wave = t >> 6;

    for (int it = 0; it < 16; ++it) {
        const int c_l = it * 4 + wave;
        const float* __restrict__ row = S + ((size_t)b * C_DIM + c0 + c_l) * C_DIM;
        float v[8];
#pragma unroll
        for (int j = 0; j < 8; ++j) v[j] = row[lane + 64 * j];

        float mx = v[0];
#pragma unroll
        for (int j = 1; j < 8; ++j) mx = fmaxf(mx, v[j]);
#pragma unroll
        for (int off = 32; off > 0; off >>= 1) mx = fmaxf(mx, __shfl_xor(mx, off));

        float sum = 0.f;
#pragma unroll
        for (int j = 0; j < 8; ++j) { v[j] = __expf(v[j] - mx); sum += v[j]; }
#pragma unroll
        for (int off = 32; off > 0; off >>= 1) sum += __shfl_xor(sum, off);

        const float inv = 1.0f / sum;
#pragma unroll
        for (int j = 0; j < 8; ++j) T[(lane + 64 * j) * 66 + c_l] = f2bf(v[j] * inv);
    }
    __syncthreads();

#pragma unroll
    for (int rep = 0; rep < 2; ++rep) {
        const int d = t + 256 * rep;
        int buf[32];
#pragma unroll
        for (int q = 0; q < 32; ++q) buf[q] = *(const int*)&T[d * 66 + q * 2];
        short* __restrict__ dst = attnT + ((size_t)b * C_DIM + d) * C_DIM + c0;
#pragma unroll
        for (int s = 0; s < 8; ++s) {
            i32x4 w = {buf[s * 4], buf[s * 4 + 1], buf[s * 4 + 2], buf[s * 4 + 3]};
            *(i32x4*)&dst[s * 8] = w;
        }
    }
}

// ---------------------------------------------------------------------------
// K3: V = x_bf16 @ attnT^T ; out = beta*V + x   — 128x128 tile, K=C=512
// A staged from fp32 x (cvt in staging), B via global_load_lds from attnT.
// grid (32, 4, 16), 256 threads.
// ---------------------------------------------------------------------------
__global__ __launch_bounds__(256) void av_kernel(const float* __restrict__ x,
                                                 const short* __restrict__ attnT,
                                                 const float* __restrict__ beta,
                                                 float* __restrict__ out) {
    const int b  = blockIdx.z;
    const int n0 = blockIdx.x * 128;
    const int d0 = blockIdx.y * 128;
    const float* __restrict__ Xb = x + (size_t)b * N_DIM * C_DIM;
    const short* __restrict__ Ab = attnT + (size_t)b * C_DIM * C_DIM;

    __shared__ short As[128 * 64];  // [n_local][c_local]
    __shared__ short Bs[128 * 64];  // [d_local][c_local]

    const int t    = threadIdx.x;
    const int lane = t & 63;
    const int wave = t >> 6;
    const int wm   = (wave >> 1) * 64;
    const int wn   = (wave & 1) * 64;
    const int fm   = lane & 15;
    const int quad = lane >> 4;

    const int rowB = t >> 3;
    const int koffB = (t & 7) * 8;

    f32x4 acc[4][4];
#pragma unroll
    for (int i = 0; i < 4; ++i)
#pragma unroll
        for (int j = 0; j < 4; ++j) acc[i][j] = (f32x4){0.f, 0.f, 0.f, 0.f};

    for (int k0 = 0; k0 < C_DIM; k0 += 64) {
        __syncthreads();
        // B: bf16 direct-to-LDS
#pragma unroll
        for (int rep = 0; rep < 4; ++rep) {
            const int r = rowB + rep * 32;
            GLOAD_LDS16(Ab + (size_t)(d0 + r) * C_DIM + k0 + koffB, &Bs[r * 64 + koffB]);
        }
        // A: fp32 -> bf16 in staging
#pragma unroll
        for (int rep = 0; rep < 8; ++rep) {
            const int g   = t + 256 * rep;
            const int row = g >> 4;
            const int seg = (g & 15) * 4;
            f32x4 v = *(const f32x4*)&Xb[(size_t)(n0 + row) * C_DIM + k0 + seg];
            bf16x4 hv = {f2bf(v[0]), f2bf(v[1]), f2bf(v[2]), f2bf(v[3])};
            *(bf16x4*)&As[row * 64 + seg] = hv;
        }
        __syncthreads();
#pragma unroll
        for (int ks = 0; ks < 64; ks += 32) {
            bf16x8 af[4], bfr[4];
#pragma unroll
            for (int s = 0; s < 4; ++s) {
                af[s]  = *(const bf16x8*)&As[(wm + s * 16 + fm) * 64 + ks + quad * 8];
                bfr[s] = *(const bf16x8*)&Bs[(wn + s * 16 + fm) * 64 + ks + quad * 8];
            }
#pragma unroll
            for (int i = 0; i < 4; ++i)
#pragma unroll
                for (int j = 0; j < 4; ++j)
                    acc[i][j] = __builtin_amdgcn_mfma_f32_16x16x32_bf16(af[i], bfr[j], acc[i][j], 0, 0, 0);
        }
    }

    const float bv = beta[0];
#pragma unroll
    for (int i = 0; i < 4; ++i)
#pragma unroll
        for (int j = 0; j < 4; ++j)
#pragma unroll
            for (int r = 0; r < 4; ++r) {
                const int nn = n0 + wm + i * 16 + quad * 4 + r;
                const int dd = d0 + wn + j * 16 + fm;
                const size_t idx = ((size_t)b * N_DIM + nn) * C_DIM + dd;
                out[idx] = bv * acc[i][j][r] + x[idx];
            }
}

extern "C" void kernel_launch(void* const* d_in, const int* in_sizes, int n_in,
                              void* d_out, int out_size, void* d_ws, size_t ws_size,
                              hipStream_t stream) {
    const float* x    = (const float*)d_in[0];
    const float* beta = (const float*)d_in[1];
    float* out = (float*)d_out;

    // workspace layout: XhT bf16 (64 MB) | S fp32 (16 MB) | attnT bf16 (8 MB)
    short* XhT  = (short*)d_ws;
    float* S    = (float*)((char*)d_ws + (size_t)BATCH * C_DIM * N_DIM * sizeof(short));
    short* attnT = (short*)((char*)S + (size_t)BATCH * C_DIM * C_DIM * sizeof(float));

    transpose_cast_kernel<<<dim3(N_DIM / 64, C_DIM / 64, BATCH), 256, 0, stream>>>(x, XhT);
    gram_kernel<<<dim3(C_DIM / 128, C_DIM / 128, BATCH), 256, 0, stream>>>(XhT, S);
    softmax_t_kernel<<<dim3(C_DIM / 64, BATCH), 256, 0, stream>>>(S, attnT);
    av_kernel<<<dim3(N_DIM / 128, C_DIM / 128, BATCH), 256, 0, stream>>>(x, attnT, beta, out);
}

// Round 3
// 393.996 us; speedup vs baseline: 1.1211x; 1.0462x over previous
//
#include <hip/hip_runtime.h>

#define BATCH 16
#define N_DIM 4096
#define C_DIM 512
#define CC (C_DIM * C_DIM)

typedef short bf16x8 __attribute__((ext_vector_type(8)));
typedef float f32x4 __attribute__((ext_vector_type(4)));
typedef int   i32x4 __attribute__((ext_vector_type(4)));

static __device__ __forceinline__ short f2bf(float f) {
    union { float f; unsigned u; } v; v.f = f;
    unsigned r = v.u + 0x7FFFu + ((v.u >> 16) & 1u);  // RNE
    return (short)(r >> 16);
}
static __device__ __forceinline__ float bf2f(short h) {
    union { unsigned u; float f; } v; v.u = ((unsigned)(unsigned short)h) << 16;
    return v.f;
}

#define GLOAD_LDS16(gp, lp) \
    __builtin_amdgcn_global_load_lds((const __attribute__((address_space(1))) void*)(gp), \
                                     (__attribute__((address_space(3))) void*)(lp), 16, 0, 0)

// ===========================================================================
// Frag-order LDS layout for a 128(row) x 64(k) bf16 tile (16 KB, 1024 slots
// of 16 B). Slot for (row, kb)  [kb = k/8]:
//   region = ((row>>6)*2 + (kb>>2))*4 + ((row>>4)&3)      (0..15)
//   slot   = region*64 + (kb&3)*16 + (row&15)
// A wave's ds_read_b128 for frag (s, ks) reads slots
//   [ ((rowhalf*2 + ks/32)*4 + s)*64 + lane ]  -> 1024 B contiguous, 0 conflicts.
// Staging instruction (w, j) covers region = w*4+j; lane -> (row, kb):
//   row = (region>>3)*64 + (region&3)*16 + (lane&15), kb = ((region>>2)&1)*4 + (lane>>4)
// ===========================================================================

// ---------------------------------------------------------------------------
// K0 prep: Xh[b][n][c] = bf16(x);  XhT[b][c][n] = bf16(x)^T
// grid (N/64, C/64, B), 256 threads
// ---------------------------------------------------------------------------
__global__ __launch_bounds__(256) void prep_kernel(const float* __restrict__ x,
                                                   short* __restrict__ Xh,
                                                   short* __restrict__ XhT,
                                                   int write_xh) {
    const int b  = blockIdx.z;
    const int n0 = blockIdx.x * 64;
    const int c0 = blockIdx.y * 64;

    __shared__ short Ts[64 * 66];

    const int t  = threadIdx.x;
    const int nl = t >> 2;
    const int cb = (t & 3) * 16;

    const float* __restrict__ src = x + ((size_t)b * N_DIM + n0 + nl) * C_DIM + c0 + cb;
    bf16x8 h0, h1;
#pragma unroll
    for (int s = 0; s < 2; ++s) {
        f32x4 v0 = *(const f32x4*)&src[s * 8];
        f32x4 v1 = *(const f32x4*)&src[s * 8 + 4];
#pragma unroll
        for (int q = 0; q < 4; ++q) {
            if (s == 0) { h0[q] = f2bf(v0[q]); h0[q + 4] = f2bf(v1[q]); }
            else        { h1[q] = f2bf(v0[q]); h1[q + 4] = f2bf(v1[q]); }
        }
    }
    if (write_xh) {
        short* __restrict__ xh = Xh + ((size_t)b * N_DIM + n0 + nl) * C_DIM + c0 + cb;
        *(bf16x8*)&xh[0] = h0;
        *(bf16x8*)&xh[8] = h1;
    }
#pragma unroll
    for (int j = 0; j < 8; ++j) {
        Ts[(cb + j) * 66 + nl]     = h0[j];
        Ts[(cb + 8 + j) * 66 + nl] = h1[j];
    }
    __syncthreads();

    const int cl = t >> 2;
    const int ng = (t & 3) * 16;
    int buf[8];
#pragma unroll
    for (int q = 0; q < 8; ++q) buf[q] = *(const int*)&Ts[cl * 66 + ng + q * 2];
    short* __restrict__ dst = XhT + ((size_t)b * C_DIM + c0 + cl) * N_DIM + n0 + ng;
    i32x4 w0 = {buf[0], buf[1], buf[2], buf[3]};
    i32x4 w1 = {buf[4], buf[5], buf[6], buf[7]};
    *(i32x4*)&dst[0] = w0;
    *(i32x4*)&dst[8] = w1;
}

// ---------------------------------------------------------------------------
// K1 gram: Spart[z][c][d] = sum over K-slice of XhT[c][n]*XhT[d][n]
// grid (4, 4, B*ns), 256 threads, 128x128 tile, BK=64, frag-order LDS.
// ---------------------------------------------------------------------------
__global__ __launch_bounds__(256) void gram_kernel(const short* __restrict__ XhT,
                                                   float* __restrict__ Spart, int ns) {
    const int z  = blockIdx.z;
    const int b  = z / ns;
    const int kslice = z - b * ns;
    const int klen  = N_DIM / ns;
    const int kbase = kslice * klen;
    const int c0 = blockIdx.x * 128;
    const int d0 = blockIdx.y * 128;
    const short* __restrict__ Xb = XhT + (size_t)b * C_DIM * N_DIM;

    __shared__ __align__(16) short As[128 * 64];
    __shared__ __align__(16) short Bs[128 * 64];

    const int t    = threadIdx.x;
    const int lane = t & 63;
    const int w    = t >> 6;
    const int wm   = (w >> 1) * 64;
    const int wn   = (w & 1) * 64;
    const int fm   = lane & 15;
    const int quad = lane >> 4;

    int srow[4], skoff[4], sslot[4];
#pragma unroll
    for (int j = 0; j < 4; ++j) {
        const int region = w * 4 + j;
        srow[j]  = (region >> 3) * 64 + (region & 3) * 16 + fm;
        skoff[j] = (((region >> 2) & 1) * 4 + quad) * 8;
        sslot[j] = (region * 64 + lane) * 8;  // short offset
    }

    f32x4 acc[4][4];
#pragma unroll
    for (int i = 0; i < 4; ++i)
#pragma unroll
        for (int j = 0; j < 4; ++j) acc[i][j] = (f32x4){0.f, 0.f, 0.f, 0.f};

    for (int k0 = kbase; k0 < kbase + klen; k0 += 64) {
        __syncthreads();
#pragma unroll
        for (int j = 0; j < 4; ++j) {
            GLOAD_LDS16(Xb + (size_t)(c0 + srow[j]) * N_DIM + k0 + skoff[j], &As[sslot[j]]);
            GLOAD_LDS16(Xb + (size_t)(d0 + srow[j]) * N_DIM + k0 + skoff[j], &Bs[sslot[j]]);
        }
        __syncthreads();
#pragma unroll
        for (int ks = 0; ks < 64; ks += 32) {
            bf16x8 af[4], bfr[4];
#pragma unroll
            for (int s = 0; s < 4; ++s) {
                af[s]  = *(const bf16x8*)&As[((((wm >> 6) * 2 + (ks >> 5)) * 4 + s) * 64 + lane) * 8];
                bfr[s] = *(const bf16x8*)&Bs[((((wn >> 6) * 2 + (ks >> 5)) * 4 + s) * 64 + lane) * 8];
            }
#pragma unroll
            for (int i = 0; i < 4; ++i)
#pragma unroll
                for (int j = 0; j < 4; ++j)
                    acc[i][j] = __builtin_amdgcn_mfma_f32_16x16x32_bf16(af[i], bfr[j], acc[i][j], 0, 0, 0);
        }
    }

    float* __restrict__ Sb = Spart + (size_t)z * CC;
#pragma unroll
    for (int i = 0; i < 4; ++i)
#pragma unroll
        for (int j = 0; j < 4; ++j)
#pragma unroll
            for (int r = 0; r < 4; ++r) {
                const int cc = c0 + wm + i * 16 + quad * 4 + r;
                const int dd = d0 + wn + j * 16 + fm;
                Sb[(size_t)cc * C_DIM + dd] = acc[i][j][r];
            }
}

// ---------------------------------------------------------------------------
// K2 softmax: attnT[b][d][c] = softmax_d(sum_ks Spart)[c][d]^T  (bf16)
// grid (C/16, B), 256 threads. 16 softmax rows per block + LDS transpose.
// ---------------------------------------------------------------------------
__global__ __launch_bounds__(256) void softmax_t_kernel(const float* __restrict__ Spart,
                                                        short* __restrict__ attnT, int ns) {
    const int c0 = blockIdx.x * 16;
    const int b  = blockIdx.y;

    __shared__ short T[512 * 18];  // [d][c_local], stride 18 shorts (36 B)

    const int t    = threadIdx.x;
    const int lane = t & 63;
    const int w    = t >> 6;

#pragma unroll
    for (int it = 0; it < 4; ++it) {
        const int cl = it * 4 + w;
        const float* __restrict__ r0 = Spart + (size_t)(b * ns) * CC + (size_t)(c0 + cl) * C_DIM;
        float v[8];
#pragma unroll
        for (int j = 0; j < 8; ++j) v[j] = r0[lane + 64 * j];
        if (ns == 2) {
            const float* __restrict__ r1 = r0 + (size_t)CC;
#pragma unroll
            for (int j = 0; j < 8; ++j) v[j] += r1[lane + 64 * j];
        }

        float mx = v[0];
#pragma unroll
        for (int j = 1; j < 8; ++j) mx = fmaxf(mx, v[j]);
#pragma unroll
        for (int off = 32; off > 0; off >>= 1) mx = fmaxf(mx, __shfl_xor(mx, off));

        float sum = 0.f;
#pragma unroll
        for (int j = 0; j < 8; ++j) { v[j] = __expf(v[j] - mx); sum += v[j]; }
#pragma unroll
        for (int off = 32; off > 0; off >>= 1) sum += __shfl_xor(sum, off);

        const float inv = 1.0f / sum;
#pragma unroll
        for (int j = 0; j < 8; ++j) T[(lane + 64 * j) * 18 + cl] = f2bf(v[j] * inv);
    }
    __syncthreads();

#pragma unroll
    for (int rep = 0; rep < 2; ++rep) {
        const int d = t + 256 * rep;
        int buf[8];
#pragma unroll
        for (int q = 0; q < 8; ++q) buf[q] = *(const int*)&T[d * 18 + q * 2];
        short* __restrict__ dst = attnT + ((size_t)b * C_DIM + d) * C_DIM + c0;
        i32x4 w0 = {buf[0], buf[1], buf[2], buf[3]};
        i32x4 w1 = {buf[4], buf[5], buf[6], buf[7]};
        *(i32x4*)&dst[0] = w0;
        *(i32x4*)&dst[8] = w1;
    }
}

// ---------------------------------------------------------------------------
// K3 av: V = Xh @ attnT^T ; out = beta*V + x   — 128x128 tile, K=512
// grid (32, 4, 16), 256 threads, frag-order LDS, both operands via
// global_load_lds when USE_XH.
// ---------------------------------------------------------------------------
template <bool USE_XH>
__global__ __launch_bounds__(256) void av_kernel(const float* __restrict__ x,
                                                 const short* __restrict__ Xh,
                                                 const short* __restrict__ attnT,
                                                 const float* __restrict__ beta,
                                                 float* __restrict__ out) {
    const int b  = blockIdx.z;
    const int n0 = blockIdx.x * 128;
    const int d0 = blockIdx.y * 128;
    const float* __restrict__ Xb32 = x + (size_t)b * N_DIM * C_DIM;
    const short* __restrict__ Xbh  = Xh + (size_t)b * N_DIM * C_DIM;
    const short* __restrict__ Ab   = attnT + (size_t)b * CC;

    __shared__ __align__(16) short As[128 * 64];
    __shared__ __align__(16) short Bs[128 * 64];

    const int t    = threadIdx.x;
    const int lane = t & 63;
    const int w    = t >> 6;
    const int wm   = (w >> 1) * 64;
    const int wn   = (w & 1) * 64;
    const int fm   = lane & 15;
    const int quad = lane >> 4;

    int srow[4], skoff[4], sslot[4];
#pragma unroll
    for (int j = 0; j < 4; ++j) {
        const int region = w * 4 + j;
        srow[j]  = (region >> 3) * 64 + (region & 3) * 16 + fm;
        skoff[j] = (((region >> 2) & 1) * 4 + quad) * 8;
        sslot[j] = (region * 64 + lane) * 8;
    }

    f32x4 acc[4][4];
#pragma unroll
    for (int i = 0; i < 4; ++i)
#pragma unroll
        for (int j = 0; j < 4; ++j) acc[i][j] = (f32x4){0.f, 0.f, 0.f, 0.f};

    for (int k0 = 0; k0 < C_DIM; k0 += 64) {
        float fa[4][8];
        if (!USE_XH) {
#pragma unroll
            for (int j = 0; j < 4; ++j) {
                const float* p = Xb32 + (size_t)(n0 + srow[j]) * C_DIM + k0 + skoff[j];
                *(f32x4*)&fa[j][0] = *(const f32x4*)&p[0];
                *(f32x4*)&fa[j][4] = *(const f32x4*)&p[4];
            }
        }
        __syncthreads();
#pragma unroll
        for (int j = 0; j < 4; ++j)
            GLOAD_LDS16(Ab + (size_t)(d0 + srow[j]) * C_DIM + k0 + skoff[j], &Bs[sslot[j]]);
        if (USE_XH) {
#pragma unroll
            for (int j = 0; j < 4; ++j)
                GLOAD_LDS16(Xbh + (size_t)(n0 + srow[j]) * C_DIM + k0 + skoff[j], &As[sslot[j]]);
        } else {
#pragma unroll
            for (int j = 0; j < 4; ++j) {
                bf16x8 hv;
#pragma unroll
                for (int q = 0; q < 8; ++q) hv[q] = f2bf(fa[j][q]);
                *(bf16x8*)&As[sslot[j]] = hv;
            }
        }
        __syncthreads();
#pragma unroll
        for (int ks = 0; ks < 64; ks += 32) {
            bf16x8 af[4], bfr[4];
#pragma unroll
            for (int s = 0; s < 4; ++s) {
                af[s]  = *(const bf16x8*)&As[((((wm >> 6) * 2 + (ks >> 5)) * 4 + s) * 64 + lane) * 8];
                bfr[s] = *(const bf16x8*)&Bs[((((wn >> 6) * 2 + (ks >> 5)) * 4 + s) * 64 + lane) * 8];
            }
#pragma unroll
            for (int i = 0; i < 4; ++i)
#pragma unroll
                for (int j = 0; j < 4; ++j)
                    acc[i][j] = __builtin_amdgcn_mfma_f32_16x16x32_bf16(af[i], bfr[j], acc[i][j], 0, 0, 0);
        }
    }

    const float bv = beta[0];
#pragma unroll
    for (int i = 0; i < 4; ++i)
#pragma unroll
        for (int j = 0; j < 4; ++j)
#pragma unroll
            for (int r = 0; r < 4; ++r) {
                const int nn = n0 + wm + i * 16 + quad * 4 + r;
                const int dd = d0 + wn + j * 16 + fm;
                const size_t idx = ((size_t)b * N_DIM + nn) * C_DIM + dd;
                const float xr = USE_XH ? bf2f(Xh[idx]) : x[idx];
                out[idx] = bv * acc[i][j][r] + xr;
            }
}

extern "C" void kernel_launch(void* const* d_in, const int* in_sizes, int n_in,
                              void* d_out, int out_size, void* d_ws, size_t ws_size,
                              hipStream_t stream) {
    const float* x    = (const float*)d_in[0];
    const float* beta = (const float*)d_in[1];
    float* out = (float*)d_out;

    const size_t sz_xhT   = (size_t)BATCH * C_DIM * N_DIM * 2;  // 64 MB
    const size_t sz_S     = (size_t)BATCH * CC * 4;             // 16 MB
    const size_t sz_attnT = (size_t)BATCH * CC * 2;             //  8 MB

    int ns; int use_xh;
    if (ws_size >= sz_xhT + 2 * sz_S + sz_attnT + sz_xhT)      { ns = 2; use_xh = 1; }
    else if (ws_size >= sz_xhT + 2 * sz_S + sz_attnT)          { ns = 2; use_xh = 0; }
    else                                                        { ns = 1; use_xh = 0; }

    char* p = (char*)d_ws;
    short* XhT   = (short*)p;
    float* Spart = (float*)(p + sz_xhT);
    short* attnT = (short*)(p + sz_xhT + (size_t)ns * sz_S);
    short* Xh    = (short*)(p + sz_xhT + (size_t)ns * sz_S + sz_attnT);

    prep_kernel<<<dim3(N_DIM / 64, C_DIM / 64, BATCH), 256, 0, stream>>>(x, Xh, XhT, use_xh);
    gram_kernel<<<dim3(4, 4, BATCH * ns), 256, 0, stream>>>(XhT, Spart, ns);
    softmax_t_kernel<<<dim3(C_DIM / 16, BATCH), 256, 0, stream>>>(Spart, attnT, ns);
    if (use_xh)
        av_kernel<true><<<dim3(N_DIM / 128, C_DIM / 128, BATCH), 256, 0, stream>>>(x, Xh, attnT, beta, out);
    else
        av_kernel<false><<<dim3(N_DIM / 128, C_DIM / 128, BATCH), 256, 0, stream>>>(x, Xh, attnT, beta, out);
}